// Round 9
// baseline (1555.253 us; speedup 1.0000x reference)
//
#include <hip/hip_runtime.h>
#include <hip/hip_bf16.h>
#include <stdint.h>

#define N_IN 250000
#define N_OUT 500000
#define INC 256
#define OUTC 128
#define KVOL 8
#define NTOT (KVOL * N_IN)
#define BN_EPS 1e-5f
#define DCHUNKS 489              // ceil(N_OUT / 1024)
#define NS (DCHUNKS * 1024)      // 500736: padded per-k count stride

typedef __bf16 bf16x8_t __attribute__((ext_vector_type(8)));
typedef __bf16 bf16x4_t __attribute__((ext_vector_type(4)));
typedef float f32x4_t __attribute__((ext_vector_type(4)));
typedef uint32_t u32x4_t __attribute__((ext_vector_type(4)));

__device__ __forceinline__ __bf16 f2bf(float x) {
  union { float f; uint32_t u; } v; v.f = x;
  uint32_t r = v.u + 0x7FFFu + ((v.u >> 16) & 1u);
  union { uint16_t s; __bf16 b; } o; o.s = (uint16_t)(r >> 16);
  return o.b;
}

__device__ __forceinline__ uint32_t pack2bf(float lo, float hi) {
  union { float f; uint32_t u; } a, b; a.f = lo; b.f = hi;
  uint32_t ra = a.u + 0x7FFFu + ((a.u >> 16) & 1u);
  uint32_t rb = b.u + 0x7FFFu + ((b.u >> 16) & 1u);
  return (ra >> 16) | (rb & 0xFFFF0000u);
}

__device__ __forceinline__ float bflo(uint32_t w) {
  union { uint32_t u; float f; } v; v.u = w << 16; return v.f;
}
__device__ __forceinline__ float bfhi(uint32_t w) {
  union { uint32_t u; float f; } v; v.u = w & 0xFFFF0000u; return v.f;
}

// ======================= conversions =======================

// x[250000][256] f32 -> xb bf16 (identical rounding to prior rounds)
__global__ void xconv_kernel(const float* __restrict__ x, uint32_t* __restrict__ xb) {
  int g = blockIdx.x * 256 + threadIdx.x;
  if (g >= N_IN * INC / 8) return;
  const float4* p = (const float4*)x + (size_t)g * 2;
  float4 v0 = p[0], v1 = p[1];
  uint4 o;
  o.x = pack2bf(v0.x, v0.y); o.y = pack2bf(v0.z, v0.w);
  o.z = pack2bf(v1.x, v1.y); o.w = pack2bf(v1.z, v1.w);
  ((uint4*)xb)[g] = o;
}

// W[k][inc][outc] fp32 -> Wt[k][outc][inc] bf16
__global__ void wconv_kernel(const float* __restrict__ W, __bf16* __restrict__ Wt) {
  int f = blockIdx.x * blockDim.x + threadIdx.x;
  if (f >= KVOL * OUTC * INC) return;
  int i = f & (INC - 1);
  int o = (f >> 8) & (OUTC - 1);
  int k = f >> 15;
  Wt[f] = f2bf(W[(k * INC + i) * OUTC + o]);
}

// ======================= per-k counting sort =======================

__global__ void hist8_kernel(const int* __restrict__ oidx, int* __restrict__ cnt8) {
  int i = blockIdx.x * 256 + threadIdx.x;
  int k = blockIdx.y;
  if (i < N_IN) atomicAdd(&cnt8[(size_t)k * NS + oidx[k * N_IN + i]], 1);
}

// int counts -> u8 counts (for the reduce's in-LDS offset rebuild)
__global__ void u8conv_kernel(const int* __restrict__ cnt8, unsigned char* __restrict__ cnt8u) {
  int g = blockIdx.x * 256 + threadIdx.x;
  if (g < KVOL * NS) cnt8u[g] = (unsigned char)min(cnt8[g], 255);
}

// per-1024-chunk exclusive scan (padded: no bounds checks); grid (DCHUNKS, 8)
__global__ void scan1s_kernel(const int* __restrict__ in, int* __restrict__ out,
                              int* __restrict__ bsum) {
  __shared__ int sd[256];
  int t = threadIdx.x;
  int s = blockIdx.y;
  const int* inp = in + (size_t)s * NS + blockIdx.x * 1024;
  int* outp = out + (size_t)s * NS + blockIdx.x * 1024;
  int4 v = *(const int4*)&inp[t * 4];
  int sm = v.x + v.y + v.z + v.w;
  sd[t] = sm; __syncthreads();
  for (int o = 1; o < 256; o <<= 1) {
    int a = (t >= o) ? sd[t - o] : 0;
    __syncthreads();
    sd[t] += a;
    __syncthreads();
  }
  int excl = sd[t] - sm;
  int4 ov;
  ov.x = excl; ov.y = excl + v.x; ov.z = excl + v.x + v.y; ov.w = excl + v.x + v.y + v.z;
  *(int4*)&outp[t * 4] = ov;
  if (t == 255) bsum[s * DCHUNKS + blockIdx.x] = sd[255];
}

// per-k scan of chunk totals -> absolute chunk bases (kept for reduce!)
__global__ void scan2s_kernel(const int* __restrict__ bsum, int* __restrict__ bsumx) {
  __shared__ int sd[512];
  int t = threadIdx.x;
  int s = blockIdx.x;
  int v = (t < DCHUNKS) ? bsum[s * DCHUNKS + t] : 0;
  sd[t] = v; __syncthreads();
  for (int o = 1; o < 512; o <<= 1) {
    int a = (t >= o) ? sd[t - o] : 0;
    __syncthreads();
    sd[t] += a;
    __syncthreads();
  }
  if (t < DCHUNKS) bsumx[s * DCHUNKS + t] = sd[t] - v;
}

// finalize fill-cursors; grid (NS/256, 8)
__global__ void scan3s_kernel(int* __restrict__ cur8, const int* __restrict__ bsumx) {
  int g = blockIdx.x * 256 + threadIdx.x;
  int s = blockIdx.y;
  if (g < NS) cur8[(size_t)s * NS + g] += bsumx[s * DCHUNKS + (g >> 10)];
}

// build per-k d-sorted source stream
__global__ void fill8_kernel(const int* __restrict__ oidx, int* __restrict__ cur8,
                             int* __restrict__ ssrc) {
  int i = blockIdx.x * 256 + threadIdx.x;
  int k = blockIdx.y;
  if (i < N_IN) {
    int d = oidx[k * N_IN + i];
    int j = atomicAdd(&cur8[(size_t)k * NS + d], 1);
    ssrc[(size_t)k * N_IN + j] = i;
  }
}

// ======================= gather-GEMM -> sequential partials =======================

#define LDS_STRIDE 264

// grid (3907, 8); 512 thr = 8 waves. Block = (k, 64 consecutive d-sorted slots).
// Gathers 64 x_bf16 rows (L3-resident: xb = 128MB < 256MB MALL, and the
// partials stream is nt/no-allocate), MFMA D[chan][voxel], writes the block's
// 64 partial rows as ONE contiguous 16KB nt-store region (sequential HBM).
__global__ __launch_bounds__(512, 1) void gemm_gather_store_kernel(
    const char* __restrict__ xbb, const __bf16* __restrict__ Wt,
    const int* __restrict__ ssrc, char* __restrict__ partials) {
  __shared__ __bf16 xs[64 * LDS_STRIDE];           // 33792 B
  __shared__ __align__(16) uint2 stg[64][34];      // 17408 B
  __shared__ int s_src[64];
  const int t = threadIdx.x;
  const int k = blockIdx.y;
  const int c0 = blockIdx.x * 64;

  if (t < 64) {
    int j = c0 + t;
    s_src[t] = (j < N_IN) ? ssrc[(size_t)k * N_IN + j] : -1;
  }
  __syncthreads();

  // gather: 32-thread group loads one row's 512B contiguously; 16 rows/pass
  #pragma unroll
  for (int ii = 0; ii < 4; ++ii) {
    int r = ii * 16 + (t >> 5);
    int off = t & 31;
    int src = s_src[r];
    uint4 v = {0u, 0u, 0u, 0u};
    if (src >= 0) v = *(const uint4*)(xbb + (size_t)src * 512 + off * 16);
    *(uint4*)&xs[r * LDS_STRIDE + off * 8] = v;
  }
  __syncthreads();

  const int w = t >> 6, l = t & 63, lr = l & 15, lg = l >> 4;
  const int m  = w >> 1;   // voxel quarter (16 rows)
  const int nh = w & 1;    // channel half (64 chans)

  f32x4_t accT[4];
  #pragma unroll
  for (int n = 0; n < 4; ++n) accT[n] = (f32x4_t){0.f, 0.f, 0.f, 0.f};

  const __bf16* Wk = Wt + (size_t)k * OUTC * INC;

  #pragma unroll
  for (int s = 0; s < 8; ++s) {
    bf16x8_t a = *(const bf16x8_t*)&xs[(m * 16 + lr) * LDS_STRIDE + s * 32 + lg * 8];
    #pragma unroll
    for (int n = 0; n < 4; ++n) {
      bf16x8_t b = *(const bf16x8_t*)&Wk[((nh * 4 + n) * 16 + lr) * INC + s * 32 + lg * 8];
      accT[n] = __builtin_amdgcn_mfma_f32_16x16x32_bf16(b, a, accT[n], 0, 0, 0);
    }
  }

  // stage: lane holds voxel m*16+lr, chans (nh*4+n)*16 + lg*4 + {0..3}
  #pragma unroll
  for (int n = 0; n < 4; ++n) {
    uint2 pk;
    pk.x = pack2bf(accT[n][0], accT[n][1]);
    pk.y = pack2bf(accT[n][2], accT[n][3]);
    stg[m * 16 + lr][(nh * 4 + n) * 4 + lg] = pk;
  }
  __syncthreads();

  // store: whole block writes 16KB contiguous (slots c0..c0+63 of stream k)
  {
    int row = t >> 3, p = t & 7;
    if (c0 + row < N_IN) {
      const u32x4_t* rp = (const u32x4_t*)&stg[row][0];
      char* dst = partials + ((size_t)k * N_IN + c0) * 256 + t * 32;
      __builtin_nontemporal_store(rp[p * 2],     (u32x4_t*)dst);
      __builtin_nontemporal_store(rp[p * 2 + 1], (u32x4_t*)(dst + 16));
    }
  }
}

// ============== chunked segmented reduce + fused BN stats ==============

// grid (DCHUNKS); 512 thr. Block = 1024 consecutive d. Wave w rebuilds stream
// w's offsets for the chunk from u8 counts + chunk base (in-LDS scan), then
// 32 groups x 16 lanes sum each d's partials across the 8 k-streams.
__global__ __launch_bounds__(512) void reduce_stats_kernel(
    const char* __restrict__ partials, const unsigned char* __restrict__ cnt8u,
    const int* __restrict__ bsumx8, char* __restrict__ accb, float* __restrict__ stats) {
  __shared__ int sd_off[8][1024];
  __shared__ unsigned char sd_cnt[8][1024];
  __shared__ float reds[8][16][8];
  __shared__ float redq[8][16][8];
  const int t = threadIdx.x;
  const int chunk = blockIdx.x;
  const int w = t >> 6, wl = t & 63;

  // wave w: scan 1024 u8 counts of stream k=w for this chunk
  {
    uint4 cv = *(const uint4*)(cnt8u + (size_t)w * NS + chunk * 1024 + wl * 16);
    const unsigned char* c = (const unsigned char*)&cv;
    int pre[16]; int tot = 0;
    #pragma unroll
    for (int e = 0; e < 16; ++e) { pre[e] = tot; tot += c[e]; }
    int incl = tot;
    #pragma unroll
    for (int off = 1; off < 64; off <<= 1) {
      int v = __shfl_up(incl, off, 64);
      if (wl >= off) incl += v;
    }
    int base = bsumx8[w * DCHUNKS + chunk] + (incl - tot);
    #pragma unroll
    for (int e = 0; e < 16; ++e) {
      sd_off[w][wl * 16 + e] = base + pre[e];
      sd_cnt[w][wl * 16 + e] = c[e];
    }
  }
  __syncthreads();

  const int lane16 = t & 15;
  const int grp = t >> 4;    // 0..31
  float ssum[8], sq[8];
  #pragma unroll
  for (int i = 0; i < 8; ++i) { ssum[i] = 0.f; sq[i] = 0.f; }

  for (int di = grp; di < 1024; di += 32) {
    int d = chunk * 1024 + di;
    if (d >= N_OUT) break;
    float a[8];
    #pragma unroll
    for (int i = 0; i < 8; ++i) a[i] = 0.f;
    for (int k = 0; k < KVOL; ++k) {
      int j0 = sd_off[k][di];
      int c = sd_cnt[k][di];
      const char* pbase = partials + ((size_t)k * N_IN + j0) * 256 + lane16 * 16;
      for (int jj = 0; jj < c; ++jj) {
        u32x4_t v = __builtin_nontemporal_load((const u32x4_t*)(pbase + (size_t)jj * 256));
        a[0] += bflo(v[0]); a[1] += bfhi(v[0]);
        a[2] += bflo(v[1]); a[3] += bfhi(v[1]);
        a[4] += bflo(v[2]); a[5] += bfhi(v[2]);
        a[6] += bflo(v[3]); a[7] += bfhi(v[3]);
      }
    }
    u32x4_t o;
    o[0] = pack2bf(a[0], a[1]); o[1] = pack2bf(a[2], a[3]);
    o[2] = pack2bf(a[4], a[5]); o[3] = pack2bf(a[6], a[7]);
    *(u32x4_t*)(accb + (size_t)d * 512 + lane16 * 16) = o;
    #pragma unroll
    for (int u = 0; u < 4; ++u) {
      float f0 = bflo(o[u]), f1 = bfhi(o[u]);
      ssum[2 * u] += f0;     sq[2 * u] += f0 * f0;
      ssum[2 * u + 1] += f1; sq[2 * u + 1] += f1 * f1;
    }
  }

  // reduce the 4 groups within each wave (lanes l, l+16, l+32, l+48)
  #pragma unroll
  for (int i = 0; i < 8; ++i) {
    ssum[i] += __shfl_xor(ssum[i], 16, 64);
    ssum[i] += __shfl_xor(ssum[i], 32, 64);
    sq[i]   += __shfl_xor(sq[i], 16, 64);
    sq[i]   += __shfl_xor(sq[i], 32, 64);
  }
  if (wl < 16) {
    #pragma unroll
    for (int i = 0; i < 8; ++i) { reds[w][wl][i] = ssum[i]; redq[w][wl][i] = sq[i]; }
  }
  __syncthreads();
  if (t < 128) {
    float acc = 0.f;
    #pragma unroll
    for (int w2 = 0; w2 < 8; ++w2) acc += reds[w2][t >> 3][t & 7];
    atomicAdd(&stats[t], acc);
  } else if (t < 256) {
    int c = t - 128;
    float acc = 0.f;
    #pragma unroll
    for (int w2 = 0; w2 < 8; ++w2) acc += redq[w2][c >> 3][c & 7];
    atomicAdd(&stats[128 + c], acc);
  }
}

// Read bf16 accum from row slot, write normalized fp32 over the full slot (nt).
__global__ void norm_kernel(char* __restrict__ outb, const float* __restrict__ stats,
                            const float* __restrict__ gamma, const float* __restrict__ beta) {
  const int t = threadIdx.x;
  const int j = t & 15;
  const int ro = t >> 4;
  const float inv_n = 1.0f / (float)N_OUT;
  float sc[8], sh[8];
  #pragma unroll
  for (int i = 0; i < 8; ++i) {
    int c = j * 8 + i;
    float mean = stats[c] * inv_n;
    float var  = stats[128 + c] * inv_n - mean * mean;
    float s = gamma[c] * rsqrtf(var + BN_EPS);
    sc[i] = s;
    sh[i] = beta[c] - mean * s;
  }
  for (int r = blockIdx.x * 16 + ro; r < N_OUT; r += gridDim.x * 16) {
    u32x4_t v = *(const u32x4_t*)(outb + (size_t)r * 512 + j * 16);
    f32x4_t o0, o1;
    #pragma unroll
    for (int u = 0; u < 4; ++u) {
      float f0 = bflo(v[u]) * sc[2 * u] + sh[2 * u];
      float f1 = bfhi(v[u]) * sc[2 * u + 1] + sh[2 * u + 1];
      if (u < 2) { o0[2 * u] = f0; o0[2 * u + 1] = f1; }
      else       { o1[2 * (u - 2)] = f0; o1[2 * (u - 2) + 1] = f1; }
    }
    __builtin_nontemporal_store(o0, (f32x4_t*)(outb + (size_t)r * 512 + j * 32));
    __builtin_nontemporal_store(o1, (f32x4_t*)(outb + (size_t)r * 512 + j * 32 + 16));
  }
}

// ======================= fallback (round-2 proven atomic path) =======================

__global__ __launch_bounds__(512, 1) void gemm_scatter_f32_kernel(
    const float* __restrict__ x, const __bf16* __restrict__ Wt,
    const int* __restrict__ out_idx, float* __restrict__ acc) {
  __shared__ __bf16 xs[64 * LDS_STRIDE];
  const int t = threadIdx.x;
  const int row0 = blockIdx.x * 64;
  #pragma unroll
  for (int i = 0; i < 8; ++i) {
    int f = t + i * 512;
    int r = f >> 6;
    int c4 = f & 63;
    int grow = row0 + r;
    float4 v = make_float4(0.f, 0.f, 0.f, 0.f);
    if (grow < N_IN) v = ((const float4*)x)[(size_t)grow * 64 + c4];
    bf16x4_t bv;
    bv[0] = f2bf(v.x); bv[1] = f2bf(v.y); bv[2] = f2bf(v.z); bv[3] = f2bf(v.w);
    *(bf16x4_t*)&xs[r * LDS_STRIDE + c4 * 4] = bv;
  }
  __syncthreads();
  const int w = t >> 6, l = t & 63, lr = l & 15, lg = l >> 4;
  f32x4_t accr[4][8];
  #pragma unroll
  for (int m = 0; m < 4; ++m)
    #pragma unroll
    for (int n = 0; n < 8; ++n)
      accr[m][n] = (f32x4_t){0.f, 0.f, 0.f, 0.f};
  const __bf16* Wkp = Wt + (size_t)w * OUTC * INC;
  #pragma unroll
  for (int s = 0; s < 8; ++s) {
    bf16x8_t a[4], b[8];
    #pragma unroll
    for (int m = 0; m < 4; ++m)
      a[m] = *(const bf16x8_t*)&xs[(m * 16 + lr) * LDS_STRIDE + s * 32 + lg * 8];
    #pragma unroll
    for (int n = 0; n < 8; ++n)
      b[n] = *(const bf16x8_t*)&Wkp[(n * 16 + lr) * INC + s * 32 + lg * 8];
    #pragma unroll
    for (int m = 0; m < 4; ++m)
      #pragma unroll
      for (int n = 0; n < 8; ++n)
        accr[m][n] = __builtin_amdgcn_mfma_f32_16x16x32_bf16(a[m], b[n], accr[m][n], 0, 0, 0);
  }
  const int* oidx = out_idx + (size_t)w * N_IN;
  #pragma unroll
  for (int m = 0; m < 4; ++m) {
    int rbase = m * 16 + lg * 4;
    #pragma unroll
    for (int reg = 0; reg < 4; ++reg) {
      int grow = row0 + rbase + reg;
      if (grow < N_IN) {
        int dst = oidx[grow];
        float* ap = acc + (size_t)dst * OUTC;
        #pragma unroll
        for (int n = 0; n < 8; ++n)
          atomicAdd(&ap[n * 16 + lr], accr[m][n][reg]);
      }
    }
  }
}

__global__ void stats_f32_kernel(const float* __restrict__ acc, float* __restrict__ stats) {
  const int t = threadIdx.x;
  const int c4 = t & 31;
  const int ro = t >> 5;
  f32x4_t s = {0.f, 0.f, 0.f, 0.f}, q = {0.f, 0.f, 0.f, 0.f};
  for (int r = blockIdx.x * 8 + ro; r < N_OUT; r += gridDim.x * 8) {
    f32x4_t v = ((const f32x4_t*)acc)[(size_t)r * 32 + c4];
    s += v; q += v * v;
  }
  __shared__ float redl[256][8];
  #pragma unroll
  for (int j = 0; j < 4; ++j) { redl[t][j] = s[j]; redl[t][4 + j] = q[j]; }
  __syncthreads();
  if (t < 32) {
    float S[4] = {0.f, 0.f, 0.f, 0.f}, Q[4] = {0.f, 0.f, 0.f, 0.f};
    for (int r2 = 0; r2 < 8; ++r2)
      #pragma unroll
      for (int j = 0; j < 4; ++j) {
        S[j] += redl[r2 * 32 + t][j];
        Q[j] += redl[r2 * 32 + t][4 + j];
      }
    #pragma unroll
    for (int j = 0; j < 4; ++j) {
      atomicAdd(&stats[t * 4 + j], S[j]);
      atomicAdd(&stats[128 + t * 4 + j], Q[j]);
    }
  }
}

__global__ void norm_f32_kernel(float* __restrict__ out, const float* __restrict__ stats,
                                const float* __restrict__ gamma, const float* __restrict__ beta) {
  const int t = threadIdx.x;
  const int c4 = t & 31;
  const int ro = t >> 5;
  const float inv_n = 1.0f / (float)N_OUT;
  float sc[4], sh[4];
  #pragma unroll
  for (int j = 0; j < 4; ++j) {
    int c = c4 * 4 + j;
    float mean = stats[c] * inv_n;
    float var  = stats[128 + c] * inv_n - mean * mean;
    float s = gamma[c] * rsqrtf(var + BN_EPS);
    sc[j] = s;
    sh[j] = beta[c] - mean * s;
  }
  for (int r = blockIdx.x * 8 + ro; r < N_OUT; r += gridDim.x * 8) {
    f32x4_t v = ((const f32x4_t*)out)[(size_t)r * 32 + c4];
    #pragma unroll
    for (int j = 0; j < 4; ++j) v[j] = v[j] * sc[j] + sh[j];
    ((f32x4_t*)out)[(size_t)r * 32 + c4] = v;
  }
}

// ======================= launch =======================

extern "C" void kernel_launch(void* const* d_in, const int* in_sizes, int n_in,
                              void* d_out, int out_size, void* d_ws, size_t ws_size,
                              hipStream_t stream) {
  const float* x     = (const float*)d_in[0];
  const float* W     = (const float*)d_in[1];
  const float* gamma = (const float*)d_in[2];
  const float* beta  = (const float*)d_in[3];
  const int*   oidx  = (const int*)d_in[4];

  // ws: partials + cnt8u + bsumx8 + stats (516.02 MB < 526.5 MB proven)
  const size_t PART_OFF   = 0;              // 512,000,000
  const size_t CNT8U_OFF  = 512000000;      //   4,005,888 (8 x NS u8)
  const size_t BSUMX_OFF  = 516005888;      //      15,648 (8 x 489 int)
  const size_t STATS_OFF  = 516021536;      //       1,024
  const size_t NEED       = 516022560;

  // transient scratch inside d_out (all dead before reduce overwrites d_out)
  char* ob = (char*)d_out;
  uint32_t* xb  = (uint32_t*)(ob);                // 128,000,000  x_bf16
  int* cnt8     = (int*)(ob + 128000000);         //  16,023,552 (8 x NS int)
  int* cur8     = (int*)(ob + 144023552);         //  16,023,552
  int* ssrc8    = (int*)(ob + 160047104);         //   8,000,000
  __bf16* Wt    = (__bf16*)(ob + 168047104);      //     524,288
  int* bsum8    = (int*)(ob + 168571392);         //      15,648

  if (ws_size >= NEED) {
    char* ws = (char*)d_ws;
    char* partials = ws + PART_OFF;
    unsigned char* cnt8u = (unsigned char*)(ws + CNT8U_OFF);
    int* bsumx8  = (int*)(ws + BSUMX_OFF);
    float* stats = (float*)(ws + STATS_OFF);

    hipMemsetAsync(cnt8, 0, (size_t)KVOL * NS * sizeof(int), stream);
    hipMemsetAsync(stats, 0, 256 * sizeof(float), stream);

    xconv_kernel<<<(N_IN * INC / 8 + 255) / 256, 256, 0, stream>>>(x, xb);
    wconv_kernel<<<(KVOL * OUTC * INC + 255) / 256, 256, 0, stream>>>(W, Wt);
    hist8_kernel<<<dim3((N_IN + 255) / 256, KVOL), 256, 0, stream>>>(oidx, cnt8);
    u8conv_kernel<<<(KVOL * NS + 255) / 256, 256, 0, stream>>>(cnt8, cnt8u);
    scan1s_kernel<<<dim3(DCHUNKS, KVOL), 256, 0, stream>>>(cnt8, cur8, bsum8);
    scan2s_kernel<<<KVOL, 512, 0, stream>>>(bsum8, bsumx8);
    scan3s_kernel<<<dim3(NS / 256, KVOL), 256, 0, stream>>>(cur8, bsumx8);
    fill8_kernel<<<dim3((N_IN + 255) / 256, KVOL), 256, 0, stream>>>(oidx, cur8, ssrc8);
    gemm_gather_store_kernel<<<dim3((N_IN + 63) / 64, KVOL), 512, 0, stream>>>(
        (const char*)xb, Wt, ssrc8, partials);
    reduce_stats_kernel<<<DCHUNKS, 512, 0, stream>>>(
        partials, cnt8u, bsumx8, ob, stats);
    norm_kernel<<<512, 256, 0, stream>>>(ob, stats, gamma, beta);
  } else {
    // fallback: proven round-2 atomic pipeline (~526 KB ws)
    __bf16* Wtf   = (__bf16*)d_ws;
    float* stats = (float*)((char*)d_ws + (size_t)KVOL * OUTC * INC * 2);
    float* out = (float*)d_out;

    hipMemsetAsync(d_out, 0, (size_t)N_OUT * OUTC * sizeof(float), stream);
    hipMemsetAsync(stats, 0, 256 * sizeof(float), stream);

    wconv_kernel<<<(KVOL * OUTC * INC + 255) / 256, 256, 0, stream>>>(W, Wtf);
    gemm_scatter_f32_kernel<<<(N_IN + 63) / 64, 512, 0, stream>>>(x, Wtf, oidx, out);
    stats_f32_kernel<<<1024, 256, 0, stream>>>(out, stats);
    norm_f32_kernel<<<2048, 256, 0, stream>>>(out, stats, gamma, beta);
  }
}